// Round 5
// baseline (445.934 us; speedup 1.0000x reference)
//
#include <hip/hip_runtime.h>

#define FFT_N 4096
#define NT 256                      // threads per block = N/16
// complex-index padding: +2 cf every 8 cf -> conflict-free for all 4 patterns
#define PADC(s) ((s) + 2 * ((s) >> 3))
#define LDS_CF 5120                 // 40960 B; 4 blocks/CU = exactly 160 KiB

struct cf { float x, y; };

__device__ __forceinline__ cf cadd(cf a, cf b) { return cf{a.x + b.x, a.y + b.y}; }
__device__ __forceinline__ cf csub(cf a, cf b) { return cf{a.x - b.x, a.y - b.y}; }
__device__ __forceinline__ cf cmul(cf a, cf b) {
    return cf{a.x * b.x - a.y * b.y, a.x * b.y + a.y * b.x};
}
// multiply by (DIR<0 ? -i : +i)
template <int DIR> __device__ __forceinline__ cf muli(cf a) {
    if constexpr (DIR < 0) return cf{a.y, -a.x};
    else                   return cf{-a.y, a.x};
}

// 16-point DFT, natural order in/out, sign of exponent = DIR (-1 fwd, +1 inv).
template <int DIR> __device__ __forceinline__ void dft16(cf v[16]) {
#pragma unroll
    for (int s = 0; s < 4; ++s) {
        cf t0 = cadd(v[s], v[s + 8]);
        cf t1 = csub(v[s], v[s + 8]);
        cf t2 = cadd(v[s + 4], v[s + 12]);
        cf t3 = csub(v[s + 4], v[s + 12]);
        cf m3 = muli<DIR>(t3);
        v[s]      = cadd(t0, t2);
        v[s + 8]  = csub(t0, t2);
        v[s + 4]  = cadd(t1, m3);
        v[s + 12] = csub(t1, m3);
    }
    constexpr float C1 = 0.9238795325112867f;  // cos(pi/8)
    constexpr float S1 = 0.3826834323650898f;  // sin(pi/8)
    constexpr float R2 = 0.7071067811865476f;  // sqrt(2)/2
    constexpr float sg = (DIR < 0) ? -1.0f : 1.0f;
    const cf w1 = cf{C1, sg * S1};
    const cf w2 = cf{R2, sg * R2};
    const cf w3 = cf{S1, sg * C1};
    const cf w6 = cf{-R2, sg * R2};
    const cf w9 = cf{-C1, -sg * S1};
    v[5]  = cmul(v[5], w1);
    v[9]  = cmul(v[9], w2);
    v[13] = cmul(v[13], w3);
    v[6]  = cmul(v[6], w2);
    v[10] = muli<DIR>(v[10]);
    v[14] = cmul(v[14], w6);
    v[7]  = cmul(v[7], w3);
    v[11] = cmul(v[11], w6);
    v[15] = cmul(v[15], w9);
    cf o[16];
#pragma unroll
    for (int p = 0; p < 4; ++p) {
        cf t0 = cadd(v[4 * p + 0], v[4 * p + 2]);
        cf t1 = csub(v[4 * p + 0], v[4 * p + 2]);
        cf t2 = cadd(v[4 * p + 1], v[4 * p + 3]);
        cf t3 = csub(v[4 * p + 1], v[4 * p + 3]);
        cf m3 = muli<DIR>(t3);
        o[p]      = cadd(t0, t2);
        o[8 + p]  = csub(t0, t2);
        o[4 + p]  = cadd(t1, m3);
        o[12 + p] = csub(t1, m3);
    }
#pragma unroll
    for (int k = 0; k < 16; ++k) v[k] = o[k];
}

// v[r] *= w^r, w = exp(i*th). Interleaved product tree: apply each w[r] as soon
// as it is formed; only w[1..8] are ever kept -> peak w-liveness ~12 regs
// (vs 30 for the full tree). Max product depth 2 (same accuracy as tree).
__device__ __forceinline__ void twiddle16(cf v[16], float th) {
    float sn, cs;
    __sincosf(th, &sn, &cs);
    cf w1 = cf{cs, sn};
    v[1] = cmul(v[1], w1);
    cf w2 = cmul(w1, w1);   v[2]  = cmul(v[2],  w2);
    cf w3 = cmul(w2, w1);   v[3]  = cmul(v[3],  w3);
    cf w4 = cmul(w2, w2);   v[4]  = cmul(v[4],  w4);
    cf w5 = cmul(w2, w3);   v[5]  = cmul(v[5],  w5);
    cf w6 = cmul(w3, w3);   v[6]  = cmul(v[6],  w6);
    cf w7 = cmul(w3, w4);   v[7]  = cmul(v[7],  w7);
    cf w8 = cmul(w4, w4);   v[8]  = cmul(v[8],  w8);
    v[9]  = cmul(v[9],  cmul(w4, w5));
    v[10] = cmul(v[10], cmul(w5, w5));
    v[11] = cmul(v[11], cmul(w5, w6));
    v[12] = cmul(v[12], cmul(w6, w6));
    v[13] = cmul(v[13], cmul(w6, w7));
    v[14] = cmul(v[14], cmul(w7, w7));
    v[15] = cmul(v[15], cmul(w7, w8));
}

// Stockham radix-16 FFT of length 4096 across a 256-thread block.
// On entry: v[r] = data[j + 256*r]. On exit: v[r] = X[j + 256*r] (natural order).
// LDS: float2, padded via PADC. Stage-0 writes are contiguous pairs (b128);
// remaining exchanges are b64. All patterns <=2-way bank aliasing (free, m136).
template <int DIR>
__device__ __forceinline__ void fft4096(cf v[16], float2* __restrict__ lds2, int j) {
    constexpr float TPI = 6.283185307179586f;
    // ---- stage 0 (Ns=1): no twiddle ----
    dft16<DIR>(v);
    __syncthreads();  // prior readers of lds2 done before overwrite
    {
        // s = 16j + r -> PADC(s) = 20j + r + 2*(r>>3); (r, r+1) contiguous & 16B-aligned
        int b = 20 * j;
#pragma unroll
        for (int r = 0; r < 16; r += 2) {
            int a = b + r + 2 * (r >> 3);
            float4 pk = make_float4(v[r].x, v[r].y, v[r + 1].x, v[r + 1].y);
            *reinterpret_cast<float4*>(&lds2[a]) = pk;  // ds_write_b128
        }
    }
    __syncthreads();
    // ---- stage 1 (Ns=16): read s = j + 256 r -> PADC = j + 2*(j>>3) + 320 r ----
    {
        int b = j + 2 * (j >> 3);
#pragma unroll
        for (int r = 0; r < 16; ++r) {
            float2 t = lds2[b + 320 * r];  // ds_read_b64
            v[r] = cf{t.x, t.y};
        }
    }
    twiddle16(v, (float)DIR * TPI * (float)(j & 15) * (1.0f / 256.0f));
    dft16<DIR>(v);
    __syncthreads();
    {
        // s = 256*(j>>4) + (j&15) + 16 r -> PADC = 320*(j>>4) + (j&15) + 2*((j&15)>>3) + 20 r
        int b = 320 * (j >> 4) + (j & 15) + 2 * ((j & 15) >> 3);
#pragma unroll
        for (int r = 0; r < 16; ++r)
            lds2[b + 20 * r] = make_float2(v[r].x, v[r].y);  // ds_write_b64
    }
    __syncthreads();
    // ---- stage 2 (Ns=256): read s = j + 256 r ----
    {
        int b = j + 2 * (j >> 3);
#pragma unroll
        for (int r = 0; r < 16; ++r) {
            float2 t = lds2[b + 320 * r];  // ds_read_b64
            v[r] = cf{t.x, t.y};
        }
    }
    twiddle16(v, (float)DIR * TPI * (float)j * (1.0f / 4096.0f));
    dft16<DIR>(v);
    // result: v[r] = X[j + 256*r]
}

// Kernel 1: W = fft(first_row) / N, single block.
__global__ void __launch_bounds__(NT) fftw_kernel(const float* __restrict__ w,
                                                  float2* __restrict__ W) {
    __shared__ __align__(16) float2 lds2[LDS_CF];
    int j = threadIdx.x;
    cf v[16];
#pragma unroll
    for (int r = 0; r < 16; ++r) {
        v[r].x = w[j + 256 * r];
        v[r].y = 0.0f;
    }
    fft4096<-1>(v, lds2, j);
    const float inv = 1.0f / (float)FFT_N;
#pragma unroll
    for (int r = 0; r < 16; ++r) {
        W[j + 256 * r] = make_float2(v[r].x * inv, v[r].y * inv);
    }
}

// Kernel 2: two rows per block packed as one complex FFT.
// z = x0 + i*x1; y0 + i*y1 = ifft(fft(z) * W)  (W pre-scaled by 1/N)
// __launch_bounds__(256,4): 4 blocks/CU (LDS 4x40KB = exactly 160 KiB);
// caps VGPR at 128 so occupancy is LDS-limited, not VGPR-limited.
__global__ void __launch_bounds__(NT, 4) circulant_main(const float* __restrict__ x,
                                                        const float2* __restrict__ W,
                                                        float* __restrict__ y) {
    __shared__ __align__(16) float2 lds2[LDS_CF];
    int j = threadIdx.x;
    long long base = (long long)blockIdx.x * 2LL * FFT_N;
    const float* x0 = x + base;
    const float* x1 = x0 + FFT_N;
    cf v[16];
#pragma unroll
    for (int r = 0; r < 16; ++r) {
        v[r].x = x0[j + 256 * r];
        v[r].y = x1[j + 256 * r];
    }
    fft4096<-1>(v, lds2, j);
#pragma unroll
    for (int r = 0; r < 16; ++r) {
        float2 wv = W[j + 256 * r];
        v[r] = cmul(v[r], cf{wv.x, wv.y});
    }
    fft4096<1>(v, lds2, j);
    float* y0 = y + base;
    float* y1 = y0 + FFT_N;
#pragma unroll
    for (int r = 0; r < 16; ++r) {
        y0[j + 256 * r] = v[r].x;
        y1[j + 256 * r] = v[r].y;
    }
}

extern "C" void kernel_launch(void* const* d_in, const int* in_sizes, int n_in,
                              void* d_out, int out_size, void* d_ws, size_t ws_size,
                              hipStream_t stream) {
    const float* x = (const float*)d_in[0];         // (16384, 4096) fp32
    const float* first_row = (const float*)d_in[1]; // (4096,) fp32
    float* y = (float*)d_out;                       // (16384, 4096) fp32
    float2* W = (float2*)d_ws;                      // 4096 complex = 32 KB scratch

    hipLaunchKernelGGL(fftw_kernel, dim3(1), dim3(NT), 0, stream, first_row, W);
    hipLaunchKernelGGL(circulant_main, dim3(16384 / 2), dim3(NT), 0, stream, x, W, y);
}

// Round 9
// 442.237 us; speedup vs baseline: 1.0084x; 1.0084x over previous
//
#include <hip/hip_runtime.h>

#define FFT_N 4096
#define NT 256                      // threads per block = N/16
// complex-index padding: +2 cf every 16 cf.
// Bank-pair = S mod 16. Derived conflict-free for ALL four access patterns:
//   stage0 write  S = 18j + r            (b128: banks (4j+2r)%32, 8 groups/8 lanes)
//   stage1/2 read S = j + 2*(j>>4) + 288r (quarter-wave: (i+2q)%16 all distinct)
//   stage1.5 write S = 288*(j>>4) + (j&15) + 18r (distinct per quarter)
// Round-5 PADC(+2 per 8) had 2-way read conflicts -> 1.68e7 conflict cycles.
#define PADC(s) ((s) + 2 * ((s) >> 4))
#define LDS_CF 4608                 // PADC(4095)+1 = 4606 -> 4608 cf = 36 KB

struct cf { float x, y; };

__device__ __forceinline__ cf cadd(cf a, cf b) { return cf{a.x + b.x, a.y + b.y}; }
__device__ __forceinline__ cf csub(cf a, cf b) { return cf{a.x - b.x, a.y - b.y}; }
__device__ __forceinline__ cf cmul(cf a, cf b) {
    return cf{a.x * b.x - a.y * b.y, a.x * b.y + a.y * b.x};
}
// multiply by (DIR<0 ? -i : +i)
template <int DIR> __device__ __forceinline__ cf muli(cf a) {
    if constexpr (DIR < 0) return cf{a.y, -a.x};
    else                   return cf{-a.y, a.x};
}

// 16-point DFT, natural order in/out, sign of exponent = DIR (-1 fwd, +1 inv).
template <int DIR> __device__ __forceinline__ void dft16(cf v[16]) {
#pragma unroll
    for (int s = 0; s < 4; ++s) {
        cf t0 = cadd(v[s], v[s + 8]);
        cf t1 = csub(v[s], v[s + 8]);
        cf t2 = cadd(v[s + 4], v[s + 12]);
        cf t3 = csub(v[s + 4], v[s + 12]);
        cf m3 = muli<DIR>(t3);
        v[s]      = cadd(t0, t2);
        v[s + 8]  = csub(t0, t2);
        v[s + 4]  = cadd(t1, m3);
        v[s + 12] = csub(t1, m3);
    }
    constexpr float C1 = 0.9238795325112867f;  // cos(pi/8)
    constexpr float S1 = 0.3826834323650898f;  // sin(pi/8)
    constexpr float R2 = 0.7071067811865476f;  // sqrt(2)/2
    constexpr float sg = (DIR < 0) ? -1.0f : 1.0f;
    const cf w1 = cf{C1, sg * S1};
    const cf w2 = cf{R2, sg * R2};
    const cf w3 = cf{S1, sg * C1};
    const cf w6 = cf{-R2, sg * R2};
    const cf w9 = cf{-C1, -sg * S1};
    v[5]  = cmul(v[5], w1);
    v[9]  = cmul(v[9], w2);
    v[13] = cmul(v[13], w3);
    v[6]  = cmul(v[6], w2);
    v[10] = muli<DIR>(v[10]);
    v[14] = cmul(v[14], w6);
    v[7]  = cmul(v[7], w3);
    v[11] = cmul(v[11], w6);
    v[15] = cmul(v[15], w9);
    cf o[16];
#pragma unroll
    for (int p = 0; p < 4; ++p) {
        cf t0 = cadd(v[4 * p + 0], v[4 * p + 2]);
        cf t1 = csub(v[4 * p + 0], v[4 * p + 2]);
        cf t2 = cadd(v[4 * p + 1], v[4 * p + 3]);
        cf t3 = csub(v[4 * p + 1], v[4 * p + 3]);
        cf m3 = muli<DIR>(t3);
        o[p]      = cadd(t0, t2);
        o[8 + p]  = csub(t0, t2);
        o[4 + p]  = cadd(t1, m3);
        o[12 + p] = csub(t1, m3);
    }
#pragma unroll
    for (int k = 0; k < 16; ++k) v[k] = o[k];
}

// v[r] *= w^r, w = exp(i*th). Interleaved product tree: apply each w[r] as soon
// as it is formed; only w[1..8] are ever kept -> peak w-liveness ~12 regs.
__device__ __forceinline__ void twiddle16(cf v[16], float th) {
    float sn, cs;
    __sincosf(th, &sn, &cs);
    cf w1 = cf{cs, sn};
    v[1] = cmul(v[1], w1);
    cf w2 = cmul(w1, w1);   v[2]  = cmul(v[2],  w2);
    cf w3 = cmul(w2, w1);   v[3]  = cmul(v[3],  w3);
    cf w4 = cmul(w2, w2);   v[4]  = cmul(v[4],  w4);
    cf w5 = cmul(w2, w3);   v[5]  = cmul(v[5],  w5);
    cf w6 = cmul(w3, w3);   v[6]  = cmul(v[6],  w6);
    cf w7 = cmul(w3, w4);   v[7]  = cmul(v[7],  w7);
    cf w8 = cmul(w4, w4);   v[8]  = cmul(v[8],  w8);
    v[9]  = cmul(v[9],  cmul(w4, w5));
    v[10] = cmul(v[10], cmul(w5, w5));
    v[11] = cmul(v[11], cmul(w5, w6));
    v[12] = cmul(v[12], cmul(w6, w6));
    v[13] = cmul(v[13], cmul(w6, w7));
    v[14] = cmul(v[14], cmul(w7, w7));
    v[15] = cmul(v[15], cmul(w7, w8));
}

// Stockham radix-16 FFT of length 4096 across a 256-thread block.
// On entry: v[r] = data[j + 256*r]. On exit: v[r] = X[j + 256*r] (natural order).
template <int DIR>
__device__ __forceinline__ void fft4096(cf v[16], float2* __restrict__ lds2, int j) {
    constexpr float TPI = 6.283185307179586f;
    // ---- stage 0 (Ns=1): no twiddle ----
    dft16<DIR>(v);
    __syncthreads();  // prior readers of lds2 done before overwrite
    {
        // s = 16j + r -> S = 18j + r; (r, r+1) contiguous & 16B-aligned
        int b = 18 * j;
#pragma unroll
        for (int r = 0; r < 16; r += 2) {
            float4 pk = make_float4(v[r].x, v[r].y, v[r + 1].x, v[r + 1].y);
            *reinterpret_cast<float4*>(&lds2[b + r]) = pk;  // ds_write_b128
        }
    }
    __syncthreads();
    // ---- stage 1 (Ns=16): read s = j + 256r -> S = j + 2*(j>>4) + 288r ----
    {
        int b = j + 2 * (j >> 4);
#pragma unroll
        for (int r = 0; r < 16; ++r) {
            float2 t = lds2[b + 288 * r];  // ds_read_b64, imm offsets
            v[r] = cf{t.x, t.y};
        }
    }
    twiddle16(v, (float)DIR * TPI * (float)(j & 15) * (1.0f / 256.0f));
    dft16<DIR>(v);
    __syncthreads();
    {
        // s = 256*(j>>4) + (j&15) + 16r -> S = 288*(j>>4) + (j&15) + 18r
        int b = 288 * (j >> 4) + (j & 15);
#pragma unroll
        for (int r = 0; r < 16; ++r)
            lds2[b + 18 * r] = make_float2(v[r].x, v[r].y);  // ds_write_b64
    }
    __syncthreads();
    // ---- stage 2 (Ns=256): read s = j + 256r ----
    {
        int b = j + 2 * (j >> 4);
#pragma unroll
        for (int r = 0; r < 16; ++r) {
            float2 t = lds2[b + 288 * r];  // ds_read_b64
            v[r] = cf{t.x, t.y};
        }
    }
    twiddle16(v, (float)DIR * TPI * (float)j * (1.0f / 4096.0f));
    dft16<DIR>(v);
    // result: v[r] = X[j + 256*r]
}

// Kernel 1: W = fft(first_row) / N, single block.
__global__ void __launch_bounds__(NT) fftw_kernel(const float* __restrict__ w,
                                                  float2* __restrict__ W) {
    __shared__ __align__(16) float2 lds2[LDS_CF];
    int j = threadIdx.x;
    cf v[16];
#pragma unroll
    for (int r = 0; r < 16; ++r) {
        v[r].x = w[j + 256 * r];
        v[r].y = 0.0f;
    }
    fft4096<-1>(v, lds2, j);
    const float inv = 1.0f / (float)FFT_N;
#pragma unroll
    for (int r = 0; r < 16; ++r) {
        W[j + 256 * r] = make_float2(v[r].x * inv, v[r].y * inv);
    }
}

// Kernel 2: two rows per block packed as one complex FFT.
// z = x0 + i*x1; y0 + i*y1 = ifft(fft(z) * W)  (W pre-scaled by 1/N)
// 36 KB LDS x 4 blocks/CU = 144 KB <= 160 KB; VGPR ~56 (round-5 measured, no spill).
__global__ void __launch_bounds__(NT, 4) circulant_main(const float* __restrict__ x,
                                                        const float2* __restrict__ W,
                                                        float* __restrict__ y) {
    __shared__ __align__(16) float2 lds2[LDS_CF];
    int j = threadIdx.x;
    long long base = (long long)blockIdx.x * 2LL * FFT_N;
    const float* x0 = x + base;
    const float* x1 = x0 + FFT_N;
    cf v[16];
#pragma unroll
    for (int r = 0; r < 16; ++r) {
        v[r].x = x0[j + 256 * r];
        v[r].y = x1[j + 256 * r];
    }
    fft4096<-1>(v, lds2, j);
#pragma unroll
    for (int r = 0; r < 16; ++r) {
        float2 wv = W[j + 256 * r];
        v[r] = cmul(v[r], cf{wv.x, wv.y});
    }
    fft4096<1>(v, lds2, j);
    float* y0 = y + base;
    float* y1 = y0 + FFT_N;
#pragma unroll
    for (int r = 0; r < 16; ++r) {
        y0[j + 256 * r] = v[r].x;
        y1[j + 256 * r] = v[r].y;
    }
}

extern "C" void kernel_launch(void* const* d_in, const int* in_sizes, int n_in,
                              void* d_out, int out_size, void* d_ws, size_t ws_size,
                              hipStream_t stream) {
    const float* x = (const float*)d_in[0];         // (16384, 4096) fp32
    const float* first_row = (const float*)d_in[1]; // (4096,) fp32
    float* y = (float*)d_out;                       // (16384, 4096) fp32
    float2* W = (float2*)d_ws;                      // 4096 complex = 32 KB scratch

    hipLaunchKernelGGL(fftw_kernel, dim3(1), dim3(NT), 0, stream, first_row, W);
    hipLaunchKernelGGL(circulant_main, dim3(16384 / 2), dim3(NT), 0, stream, x, W, y);
}